// Round 1
// baseline (1418.422 us; speedup 1.0000x reference)
//
#include <hip/hip_runtime.h>

// Sparse graph attention (CoreAttention):
//   score[e,h] = exp(clip(dot(k[src],q[dst])/sqrt(D), -5, 5))
//   out[n,h,:] = sum_{e: dst==n} v[src]*score / (sum score + 1e-6)
// B=1, N=50000, H=8, D=16, E=800000.

#define HEADS 8
#define DIM 16

// One 4-lane group per (edge, head). Lane d4 handles floats [4*d4, 4*d4+4).
__global__ void edge_scatter_kernel(const float4* __restrict__ q4,
                                    const float4* __restrict__ k4,
                                    const float4* __restrict__ v4,
                                    const int* __restrict__ src_idx,
                                    const int* __restrict__ dst_idx,
                                    float* __restrict__ wV,   // [N*H*D] accum (= d_out)
                                    float* __restrict__ Z,    // [N*H] accum
                                    int E) {
    int t = blockIdx.x * blockDim.x + threadIdx.x;
    int e = t >> 5;                  // 32 threads per edge (8 heads x 4 lanes)
    if (e >= E) return;
    int sub = t & 31;
    int h   = sub >> 2;
    int d4  = sub & 3;

    int src = src_idx[e];
    int dst = dst_idx[e];

    // Each lane: one float4 of k[src,h] and q[dst,h]
    float4 kv = k4[(size_t)(src * HEADS + h) * 4 + d4];
    float4 qv = q4[(size_t)(dst * HEADS + h) * 4 + d4];
    float dot = kv.x * qv.x + kv.y * qv.y + kv.z * qv.z + kv.w * qv.w;
    // reduce across the 4-lane group (lanes 4k..4k+3)
    dot += __shfl_xor(dot, 1, 64);
    dot += __shfl_xor(dot, 2, 64);

    float s = dot * 0.25f;                       // / sqrt(16)
    s = fminf(fmaxf(s, -5.0f), 5.0f);
    float score = expf(s);

    float4 vv = v4[(size_t)(src * HEADS + h) * 4 + d4];
    float* out = wV + (size_t)(dst * HEADS + h) * DIM + d4 * 4;
    atomicAdd(out + 0, vv.x * score);
    atomicAdd(out + 1, vv.y * score);
    atomicAdd(out + 2, vv.z * score);
    atomicAdd(out + 3, vv.w * score);
    if (d4 == 0) atomicAdd(Z + (size_t)dst * HEADS + h, score);
}

// out[n,h,d] /= (Z[n,h] + 1e-6), float4-vectorized
__global__ void norm_kernel(float4* __restrict__ out4,
                            const float* __restrict__ Z,
                            int n_vec4) {   // N*H*4
    int t = blockIdx.x * blockDim.x + threadIdx.x;
    if (t >= n_vec4) return;
    int nh = t >> 2;
    float inv = 1.0f / (Z[nh] + 1e-6f);
    float4 w = out4[t];
    w.x *= inv; w.y *= inv; w.z *= inv; w.w *= inv;
    out4[t] = w;
}

extern "C" void kernel_launch(void* const* d_in, const int* in_sizes, int n_in,
                              void* d_out, int out_size, void* d_ws, size_t ws_size,
                              hipStream_t stream) {
    const float* q = (const float*)d_in[0];
    const float* k = (const float*)d_in[1];
    const float* v = (const float*)d_in[2];
    const int* edge = (const int*)d_in[3];

    const int E = in_sizes[3] / 2;
    const int N = in_sizes[0] / (HEADS * DIM);

    float* out = (float*)d_out;
    float* Z   = (float*)d_ws;          // N*H floats

    // zero accumulators every call (graph-capture-safe)
    hipMemsetAsync(d_out, 0, (size_t)out_size * sizeof(float), stream);
    hipMemsetAsync(Z, 0, (size_t)N * HEADS * sizeof(float), stream);

    const int* src_idx = edge;          // edge_index[0]
    const int* dst_idx = edge + E;      // edge_index[1]

    {
        long long threads = (long long)E * 32;
        int block = 256;
        int grid = (int)((threads + block - 1) / block);
        edge_scatter_kernel<<<grid, block, 0, stream>>>(
            (const float4*)q, (const float4*)k, (const float4*)v,
            src_idx, dst_idx, out, Z, E);
    }
    {
        int n_vec4 = N * HEADS * 4;
        int block = 256;
        int grid = (n_vec4 + block - 1) / block;
        norm_kernel<<<grid, block, 0, stream>>>((float4*)out, Z, n_vec4);
    }
}

// Round 2
// 233.732 us; speedup vs baseline: 6.0686x; 6.0686x over previous
//
#include <hip/hip_runtime.h>

// Sparse graph attention (CoreAttention), CSR-by-dst two-phase formulation.
//   score[e,h] = exp(clip(dot(k[src],q[dst])/sqrt(D), -5, 5))
//   out[n,h,:] = sum_{e: dst==n} v[src]*score / (sum score + 1e-6)
// B=1, N=50000, H=8, D=16, E=800000.

#define HEADS 8
#define DIM 16

// ---- Phase A: build CSR by destination ----

__global__ void hist_kernel(const int* __restrict__ dst_idx, int* __restrict__ counts, int E) {
    int e = blockIdx.x * blockDim.x + threadIdx.x;
    if (e < E) atomicAdd(&counts[dst_idx[e]], 1);
}

// Per-block inclusive scan of 256-elem chunks (Hillis-Steele in LDS).
__global__ void scan1_kernel(const int* __restrict__ counts, int* __restrict__ scanned,
                             int* __restrict__ blocksums, int n) {
    __shared__ int sh[256];
    int i = blockIdx.x * 256 + threadIdx.x;
    sh[threadIdx.x] = (i < n) ? counts[i] : 0;
    __syncthreads();
    for (int off = 1; off < 256; off <<= 1) {
        int t = (threadIdx.x >= off) ? sh[threadIdx.x - off] : 0;
        __syncthreads();
        sh[threadIdx.x] += t;
        __syncthreads();
    }
    if (i < n) scanned[i] = sh[threadIdx.x];            // inclusive
    if (threadIdx.x == 255) blocksums[blockIdx.x] = sh[255];
}

// Single-block exclusive scan of block sums (nb <= 256; nb = ceil(50000/256) = 196).
__global__ void scan2_kernel(const int* __restrict__ blocksums, int* __restrict__ bsum_ex, int nb) {
    __shared__ int sh[256];
    int t = threadIdx.x;
    int orig = (t < nb) ? blocksums[t] : 0;
    sh[t] = orig;
    __syncthreads();
    for (int off = 1; off < 256; off <<= 1) {
        int x = (t >= off) ? sh[t - off] : 0;
        __syncthreads();
        sh[t] += x;
        __syncthreads();
    }
    if (t < nb) bsum_ex[t] = sh[t] - orig;              // exclusive
}

__global__ void rowptr_kernel(const int* __restrict__ counts, const int* __restrict__ scanned,
                              const int* __restrict__ bsum_ex,
                              int* __restrict__ rowptr, int* __restrict__ cursor,
                              int n, int E) {
    int i = blockIdx.x * blockDim.x + threadIdx.x;
    if (i < n) {
        int ex = scanned[i] - counts[i] + bsum_ex[i >> 8];   // exclusive prefix
        rowptr[i] = ex;
        cursor[i] = ex;
    } else if (i == n) {
        rowptr[n] = E;
    }
}

__global__ void scatter_kernel(const int* __restrict__ src_idx, const int* __restrict__ dst_idx,
                               int* __restrict__ cursor, int* __restrict__ sorted_src, int E) {
    int e = blockIdx.x * blockDim.x + threadIdx.x;
    if (e < E) {
        int d = dst_idx[e];
        int pos = atomicAdd(&cursor[d], 1);
        sorted_src[pos] = src_idx[e];
    }
}

// ---- Phase B: per-dst-node gather + register accumulation + fused normalize ----
// One 64-lane wave per dst node. lane = h*8 + dp; each lane owns float2 at dim 2*dp.
__global__ void gather_kernel(const float2* __restrict__ q2, const float2* __restrict__ k2,
                              const float2* __restrict__ v2,
                              const int* __restrict__ rowptr, const int* __restrict__ sorted_src,
                              float2* __restrict__ out2, int n) {
    int wave = (blockIdx.x * blockDim.x + threadIdx.x) >> 6;
    if (wave >= n) return;
    int lane = threadIdx.x & 63;
    int h  = lane >> 3;
    int dp = lane & 7;
    int node = wave;

    float2 qv = q2[((size_t)node * HEADS + h) * 8 + dp];
    qv.x *= 0.25f; qv.y *= 0.25f;                        // fold 1/sqrt(D)

    float2 acc = make_float2(0.f, 0.f);
    float zsum = 0.f;
    int beg = rowptr[node], end = rowptr[node + 1];
    for (int j = beg; j < end; ++j) {
        int src = sorted_src[j];                          // wave-uniform broadcast
        size_t base = ((size_t)src * HEADS + h) * 8 + dp;
        float2 kv = k2[base];
        float p = qv.x * kv.x + qv.y * kv.y;
        p += __shfl_xor(p, 1, 64);                        // reduce over 8-lane head group
        p += __shfl_xor(p, 2, 64);
        p += __shfl_xor(p, 4, 64);
        p = fminf(fmaxf(p, -5.f), 5.f);
        float score = __expf(p);
        float2 vv = v2[base];
        acc.x += vv.x * score;
        acc.y += vv.y * score;
        zsum += score;
    }
    float inv = 1.f / (zsum + 1e-6f);
    out2[((size_t)node * HEADS + h) * 8 + dp] = make_float2(acc.x * inv, acc.y * inv);
}

extern "C" void kernel_launch(void* const* d_in, const int* in_sizes, int n_in,
                              void* d_out, int out_size, void* d_ws, size_t ws_size,
                              hipStream_t stream) {
    const float* q = (const float*)d_in[0];
    const float* k = (const float*)d_in[1];
    const float* v = (const float*)d_in[2];
    const int* edge = (const int*)d_in[3];

    const int E = in_sizes[3] / 2;
    const int N = in_sizes[0] / (HEADS * DIM);
    const int nb = (N + 255) / 256;

    const int* src_idx = edge;
    const int* dst_idx = edge + E;

    // workspace layout (ints)
    int* counts     = (int*)d_ws;
    int* scanned    = counts + N;
    int* rowptr     = scanned + N;
    int* cursor     = rowptr + (N + 1);
    int* sorted_src = cursor + N;
    int* blocksums  = sorted_src + E;
    int* bsum_ex    = blocksums + nb;

    hipMemsetAsync(counts, 0, (size_t)N * sizeof(int), stream);

    hist_kernel<<<(E + 255) / 256, 256, 0, stream>>>(dst_idx, counts, E);
    scan1_kernel<<<nb, 256, 0, stream>>>(counts, scanned, blocksums, N);
    scan2_kernel<<<1, 256, 0, stream>>>(blocksums, bsum_ex, nb);
    rowptr_kernel<<<(N + 256) / 256, 256, 0, stream>>>(counts, scanned, bsum_ex,
                                                       rowptr, cursor, N, E);
    scatter_kernel<<<(E + 255) / 256, 256, 0, stream>>>(src_idx, dst_idx, cursor, sorted_src, E);

    {
        long long threads = (long long)N * 64;
        int block = 256;
        int grid = (int)((threads + block - 1) / block);
        gather_kernel<<<grid, block, 0, stream>>>((const float2*)q, (const float2*)k,
                                                  (const float2*)v, rowptr, sorted_src,
                                                  (float2*)d_out, N);
    }
}

// Round 3
// 207.335 us; speedup vs baseline: 6.8412x; 1.1273x over previous
//
#include <hip/hip_runtime.h>

// Sparse graph attention (CoreAttention), CSR-by-dst two-phase formulation.
//   score[e,h] = exp(clip(dot(k[src],q[dst])/sqrt(D), -5, 5))
//   out[n,h,:] = sum_{e: dst==n} v[src]*score / (sum score + 1e-6)
// B=1, N=50000, H=8, D=16, E=800000.

#define HEADS 8
#define DIM 16

// ---- Phase A: build CSR by destination ----

// 4 edges per thread via int4.
__global__ void hist_kernel(const int* __restrict__ dst_idx, int* __restrict__ counts, int E) {
    int i = blockIdx.x * blockDim.x + threadIdx.x;
    int base = i * 4;
    if (base + 3 < E) {
        int4 d = *(const int4*)(dst_idx + base);
        atomicAdd(&counts[d.x], 1);
        atomicAdd(&counts[d.y], 1);
        atomicAdd(&counts[d.z], 1);
        atomicAdd(&counts[d.w], 1);
    } else {
        for (int e = base; e < E; ++e) atomicAdd(&counts[dst_idx[e]], 1);
    }
}

// Per-block inclusive scan of 256-elem chunks (Hillis-Steele in LDS).
__global__ void scan1_kernel(const int* __restrict__ counts, int* __restrict__ scanned,
                             int* __restrict__ blocksums, int n) {
    __shared__ int sh[256];
    int i = blockIdx.x * 256 + threadIdx.x;
    sh[threadIdx.x] = (i < n) ? counts[i] : 0;
    __syncthreads();
    for (int off = 1; off < 256; off <<= 1) {
        int t = (threadIdx.x >= off) ? sh[threadIdx.x - off] : 0;
        __syncthreads();
        sh[threadIdx.x] += t;
        __syncthreads();
    }
    if (i < n) scanned[i] = sh[threadIdx.x];            // inclusive
    if (threadIdx.x == 255) blocksums[blockIdx.x] = sh[255];
}

// Single-block exclusive scan of block sums (nb <= 256).
__global__ void scan2_kernel(const int* __restrict__ blocksums, int* __restrict__ bsum_ex, int nb) {
    __shared__ int sh[256];
    int t = threadIdx.x;
    int orig = (t < nb) ? blocksums[t] : 0;
    sh[t] = orig;
    __syncthreads();
    for (int off = 1; off < 256; off <<= 1) {
        int x = (t >= off) ? sh[t - off] : 0;
        __syncthreads();
        sh[t] += x;
        __syncthreads();
    }
    if (t < nb) bsum_ex[t] = sh[t] - orig;              // exclusive
}

__global__ void rowptr_kernel(const int* __restrict__ counts, const int* __restrict__ scanned,
                              const int* __restrict__ bsum_ex,
                              int* __restrict__ rowptr, int* __restrict__ cursor,
                              int n, int E) {
    int i = blockIdx.x * blockDim.x + threadIdx.x;
    if (i < n) {
        int ex = scanned[i] - counts[i] + bsum_ex[i >> 8];   // exclusive prefix
        rowptr[i] = ex;
        cursor[i] = ex;
    } else if (i == n) {
        rowptr[n] = E;
    }
}

// 4 edges per thread via int4.
__global__ void scatter_kernel(const int* __restrict__ src_idx, const int* __restrict__ dst_idx,
                               int* __restrict__ cursor, int* __restrict__ sorted_src, int E) {
    int i = blockIdx.x * blockDim.x + threadIdx.x;
    int base = i * 4;
    if (base + 3 < E) {
        int4 s = *(const int4*)(src_idx + base);
        int4 d = *(const int4*)(dst_idx + base);
        sorted_src[atomicAdd(&cursor[d.x], 1)] = s.x;
        sorted_src[atomicAdd(&cursor[d.y], 1)] = s.y;
        sorted_src[atomicAdd(&cursor[d.z], 1)] = s.z;
        sorted_src[atomicAdd(&cursor[d.w], 1)] = s.w;
    } else {
        for (int e = base; e < E; ++e)
            sorted_src[atomicAdd(&cursor[dst_idx[e]], 1)] = src_idx[e];
    }
}

// ---- Phase B: per-dst-node gather, 2 edges per wave-iteration ----
// 32 lanes per edge: lane l32 owns float4 at dim offset l32*4 of the 128-float row.
// Head h = l32 >> 2 (4 lanes per head, D=16 = 4 float4s).
__global__ void gather_kernel(const float4* __restrict__ q4, const float4* __restrict__ k4,
                              const float4* __restrict__ v4,
                              const int* __restrict__ rowptr, const int* __restrict__ sorted_src,
                              float4* __restrict__ out4, int n) {
    int wave = (blockIdx.x * blockDim.x + threadIdx.x) >> 6;
    if (wave >= n) return;
    int lane = threadIdx.x & 63;
    int l32  = lane & 31;
    int half = lane >> 5;

    size_t qbase = (size_t)wave * 32 + l32;
    float4 qv = q4[qbase];
    qv.x *= 0.25f; qv.y *= 0.25f; qv.z *= 0.25f; qv.w *= 0.25f;   // fold 1/sqrt(D)

    float4 acc = make_float4(0.f, 0.f, 0.f, 0.f);
    float zsum = 0.f;
    int beg = rowptr[wave], end = rowptr[wave + 1];

    for (int j = beg; j < end; j += 2) {
        int my  = j + half;
        int idx = (my < end) ? my : (end - 1);
        int src = sorted_src[idx];
        size_t base = (size_t)src * 32 + l32;
        float4 kv = k4[base];
        float p = qv.x * kv.x + qv.y * kv.y + qv.z * kv.z + qv.w * kv.w;
        p += __shfl_xor(p, 1, 64);                 // reduce over 4-lane head group
        p += __shfl_xor(p, 2, 64);
        p = fminf(fmaxf(p, -5.f), 5.f);
        float score = __expf(p);
        if (my >= end) score = 0.f;
        float4 vv = v4[base];
        acc.x += vv.x * score;
        acc.y += vv.y * score;
        acc.z += vv.z * score;
        acc.w += vv.w * score;
        zsum += score;
    }

    // combine the two halves
    acc.x += __shfl_xor(acc.x, 32, 64);
    acc.y += __shfl_xor(acc.y, 32, 64);
    acc.z += __shfl_xor(acc.z, 32, 64);
    acc.w += __shfl_xor(acc.w, 32, 64);
    zsum  += __shfl_xor(zsum,  32, 64);

    float inv = 1.f / (zsum + 1e-6f);
    if (half == 0) {
        out4[qbase] = make_float4(acc.x * inv, acc.y * inv, acc.z * inv, acc.w * inv);
    }
}

extern "C" void kernel_launch(void* const* d_in, const int* in_sizes, int n_in,
                              void* d_out, int out_size, void* d_ws, size_t ws_size,
                              hipStream_t stream) {
    const float* q = (const float*)d_in[0];
    const float* k = (const float*)d_in[1];
    const float* v = (const float*)d_in[2];
    const int* edge = (const int*)d_in[3];

    const int E = in_sizes[3] / 2;
    const int N = in_sizes[0] / (HEADS * DIM);
    const int nb = (N + 255) / 256;

    const int* src_idx = edge;
    const int* dst_idx = edge + E;

    // workspace layout (ints)
    int* counts     = (int*)d_ws;
    int* scanned    = counts + N;
    int* rowptr     = scanned + N;
    int* cursor     = rowptr + (N + 1);
    int* sorted_src = cursor + N;
    int* blocksums  = sorted_src + E;
    int* bsum_ex    = blocksums + nb;

    hipMemsetAsync(counts, 0, (size_t)N * sizeof(int), stream);

    {
        int threads = (E + 3) / 4;
        hist_kernel<<<(threads + 255) / 256, 256, 0, stream>>>(dst_idx, counts, E);
    }
    scan1_kernel<<<nb, 256, 0, stream>>>(counts, scanned, blocksums, N);
    scan2_kernel<<<1, 256, 0, stream>>>(blocksums, bsum_ex, nb);
    rowptr_kernel<<<(N + 256) / 256, 256, 0, stream>>>(counts, scanned, bsum_ex,
                                                       rowptr, cursor, N, E);
    {
        int threads = (E + 3) / 4;
        scatter_kernel<<<(threads + 255) / 256, 256, 0, stream>>>(src_idx, dst_idx, cursor,
                                                                  sorted_src, E);
    }
    {
        long long threads = (long long)N * 64;
        int block = 256;
        int grid = (int)((threads + block - 1) / block);
        gather_kernel<<<grid, block, 0, stream>>>((const float4*)q, (const float4*)k,
                                                  (const float4*)v, rowptr, sorted_src,
                                                  (float4*)d_out, N);
    }
}

// Round 4
// 206.477 us; speedup vs baseline: 6.8696x; 1.0042x over previous
//
#include <hip/hip_runtime.h>

// Sparse graph attention (CoreAttention), CSR-by-dst two-phase formulation.
//   score[e,h] = exp(clip(dot(k[src],q[dst])/sqrt(D), -5, 5))
//   out[n,h,:] = sum_{e: dst==n} v[src]*score / (sum score + 1e-6)
// B=1, N=50000, H=8, D=16, E=800000.

#define HEADS 8
#define DIM 16

// ---- Phase A: build CSR by destination ----

// 4 edges per thread via int4.
__global__ void hist_kernel(const int* __restrict__ dst_idx, int* __restrict__ counts, int E) {
    int i = blockIdx.x * blockDim.x + threadIdx.x;
    int base = i * 4;
    if (base + 3 < E) {
        int4 d = *(const int4*)(dst_idx + base);
        atomicAdd(&counts[d.x], 1);
        atomicAdd(&counts[d.y], 1);
        atomicAdd(&counts[d.z], 1);
        atomicAdd(&counts[d.w], 1);
    } else {
        for (int e = base; e < E; ++e) atomicAdd(&counts[dst_idx[e]], 1);
    }
}

// Per-block inclusive scan of 256-elem chunks (Hillis-Steele in LDS).
__global__ void scan1_kernel(const int* __restrict__ counts, int* __restrict__ scanned,
                             int* __restrict__ blocksums, int n) {
    __shared__ int sh[256];
    int i = blockIdx.x * 256 + threadIdx.x;
    sh[threadIdx.x] = (i < n) ? counts[i] : 0;
    __syncthreads();
    for (int off = 1; off < 256; off <<= 1) {
        int t = (threadIdx.x >= off) ? sh[threadIdx.x - off] : 0;
        __syncthreads();
        sh[threadIdx.x] += t;
        __syncthreads();
    }
    if (i < n) scanned[i] = sh[threadIdx.x];            // inclusive
    if (threadIdx.x == 255) blocksums[blockIdx.x] = sh[255];
}

// rowptr + inline scan of blocksums (each block reduces its own prefix).
__global__ void rowptr_kernel(const int* __restrict__ counts, const int* __restrict__ scanned,
                              const int* __restrict__ blocksums,
                              int* __restrict__ rowptr, int* __restrict__ cursor,
                              int n, int nb, int E) {
    __shared__ int red[256];
    int b = blockIdx.x;
    int t = threadIdx.x;
    int val = 0;
    for (int t2 = t; t2 < b; t2 += 256) val += blocksums[t2];
    red[t] = val;
    __syncthreads();
    for (int off = 128; off > 0; off >>= 1) {
        if (t < off) red[t] += red[t + off];
        __syncthreads();
    }
    int base = red[0];
    int i = b * 256 + t;
    if (i < n) {
        int ex = scanned[i] - counts[i] + base;          // exclusive prefix
        rowptr[i] = ex;
        cursor[i] = ex;
    }
    if (i == n) rowptr[n] = E;
}

// 4 edges per thread via int4.
__global__ void scatter_kernel(const int* __restrict__ src_idx, const int* __restrict__ dst_idx,
                               int* __restrict__ cursor, int* __restrict__ sorted_src, int E) {
    int i = blockIdx.x * blockDim.x + threadIdx.x;
    int base = i * 4;
    if (base + 3 < E) {
        int4 s = *(const int4*)(src_idx + base);
        int4 d = *(const int4*)(dst_idx + base);
        sorted_src[atomicAdd(&cursor[d.x], 1)] = s.x;
        sorted_src[atomicAdd(&cursor[d.y], 1)] = s.y;
        sorted_src[atomicAdd(&cursor[d.z], 1)] = s.z;
        sorted_src[atomicAdd(&cursor[d.w], 1)] = s.w;
    } else {
        for (int e = base; e < E; ++e)
            sorted_src[atomicAdd(&cursor[dst_idx[e]], 1)] = src_idx[e];
    }
}

// ---- Phase B: per-dst-node gather, 8 edges per wave-iteration ----
// 8 lanes per edge; lane l8 owns head l8 (4 float4 = 16 dims). Dot is fully
// in-lane (no shuffles in loop); 8 independent row-gathers in flight per iter.
__global__ void gather_kernel(const float4* __restrict__ q4, const float4* __restrict__ k4,
                              const float4* __restrict__ v4,
                              const int* __restrict__ rowptr, const int* __restrict__ sorted_src,
                              float4* __restrict__ out4, int n) {
    int wave = (blockIdx.x * blockDim.x + threadIdx.x) >> 6;
    if (wave >= n) return;
    int lane = threadIdx.x & 63;
    int g  = lane >> 3;              // edge slot 0..7 within iteration
    int l8 = lane & 7;               // head index

    size_t qbase = (size_t)wave * 32 + l8 * 4;
    float4 q0 = q4[qbase + 0], q1 = q4[qbase + 1], q2 = q4[qbase + 2], q3 = q4[qbase + 3];
    q0.x *= 0.25f; q0.y *= 0.25f; q0.z *= 0.25f; q0.w *= 0.25f;
    q1.x *= 0.25f; q1.y *= 0.25f; q1.z *= 0.25f; q1.w *= 0.25f;
    q2.x *= 0.25f; q2.y *= 0.25f; q2.z *= 0.25f; q2.w *= 0.25f;
    q3.x *= 0.25f; q3.y *= 0.25f; q3.z *= 0.25f; q3.w *= 0.25f;

    float4 a0 = make_float4(0,0,0,0), a1 = a0, a2 = a0, a3 = a0;
    float zsum = 0.f;
    int beg = rowptr[wave], end = rowptr[wave + 1];

    if (beg < end) {
        int src_cur = sorted_src[min(beg + g, end - 1)];
        for (int j = beg; j < end; j += 8) {
            int my = j + g;
            int src = src_cur;
            src_cur = sorted_src[min(j + 8 + g, end - 1)];   // prefetch next iter's idx

            size_t base = (size_t)src * 32 + l8 * 4;
            float4 k0 = k4[base + 0], k1 = k4[base + 1], k2 = k4[base + 2], k3 = k4[base + 3];
            float p = q0.x*k0.x + q0.y*k0.y + q0.z*k0.z + q0.w*k0.w
                    + q1.x*k1.x + q1.y*k1.y + q1.z*k1.z + q1.w*k1.w
                    + q2.x*k2.x + q2.y*k2.y + q2.z*k2.z + q2.w*k2.w
                    + q3.x*k3.x + q3.y*k3.y + q3.z*k3.z + q3.w*k3.w;
            p = fminf(fmaxf(p, -5.f), 5.f);
            float score = __expf(p);
            if (my >= end) score = 0.f;

            float4 v0 = v4[base + 0], v1 = v4[base + 1], v2 = v4[base + 2], v3 = v4[base + 3];
            a0.x += v0.x*score; a0.y += v0.y*score; a0.z += v0.z*score; a0.w += v0.w*score;
            a1.x += v1.x*score; a1.y += v1.y*score; a1.z += v1.z*score; a1.w += v1.w*score;
            a2.x += v2.x*score; a2.y += v2.y*score; a2.z += v2.z*score; a2.w += v2.w*score;
            a3.x += v3.x*score; a3.y += v3.y*score; a3.z += v3.z*score; a3.w += v3.w*score;
            zsum += score;
        }
    }

    // reduce the 8 edge-slots (lanes differing in bits 3..5)
    #pragma unroll
    for (int off = 8; off <= 32; off <<= 1) {
        a0.x += __shfl_xor(a0.x, off, 64); a0.y += __shfl_xor(a0.y, off, 64);
        a0.z += __shfl_xor(a0.z, off, 64); a0.w += __shfl_xor(a0.w, off, 64);
        a1.x += __shfl_xor(a1.x, off, 64); a1.y += __shfl_xor(a1.y, off, 64);
        a1.z += __shfl_xor(a1.z, off, 64); a1.w += __shfl_xor(a1.w, off, 64);
        a2.x += __shfl_xor(a2.x, off, 64); a2.y += __shfl_xor(a2.y, off, 64);
        a2.z += __shfl_xor(a2.z, off, 64); a2.w += __shfl_xor(a2.w, off, 64);
        a3.x += __shfl_xor(a3.x, off, 64); a3.y += __shfl_xor(a3.y, off, 64);
        a3.z += __shfl_xor(a3.z, off, 64); a3.w += __shfl_xor(a3.w, off, 64);
        zsum += __shfl_xor(zsum, off, 64);
    }

    float inv = 1.f / (zsum + 1e-6f);
    if (g == 0) {
        out4[qbase + 0] = make_float4(a0.x*inv, a0.y*inv, a0.z*inv, a0.w*inv);
        out4[qbase + 1] = make_float4(a1.x*inv, a1.y*inv, a1.z*inv, a1.w*inv);
        out4[qbase + 2] = make_float4(a2.x*inv, a2.y*inv, a2.z*inv, a2.w*inv);
        out4[qbase + 3] = make_float4(a3.x*inv, a3.y*inv, a3.z*inv, a3.w*inv);
    }
}

extern "C" void kernel_launch(void* const* d_in, const int* in_sizes, int n_in,
                              void* d_out, int out_size, void* d_ws, size_t ws_size,
                              hipStream_t stream) {
    const float* q = (const float*)d_in[0];
    const float* k = (const float*)d_in[1];
    const float* v = (const float*)d_in[2];
    const int* edge = (const int*)d_in[3];

    const int E = in_sizes[3] / 2;
    const int N = in_sizes[0] / (HEADS * DIM);
    const int nb = (N + 255) / 256;

    const int* src_idx = edge;
    const int* dst_idx = edge + E;

    // workspace layout (ints)
    int* counts     = (int*)d_ws;
    int* scanned    = counts + N;
    int* rowptr     = scanned + N;
    int* cursor     = rowptr + (N + 1);
    int* sorted_src = cursor + N;
    int* blocksums  = sorted_src + E;

    hipMemsetAsync(counts, 0, (size_t)N * sizeof(int), stream);

    {
        int threads = (E + 3) / 4;
        hist_kernel<<<(threads + 255) / 256, 256, 0, stream>>>(dst_idx, counts, E);
    }
    scan1_kernel<<<nb, 256, 0, stream>>>(counts, scanned, blocksums, N);
    {
        int blocks = (N + 256) / 256;   // cover i == N for the sentinel
        rowptr_kernel<<<blocks, 256, 0, stream>>>(counts, scanned, blocksums,
                                                  rowptr, cursor, N, nb, E);
    }
    {
        int threads = (E + 3) / 4;
        scatter_kernel<<<(threads + 255) / 256, 256, 0, stream>>>(src_idx, dst_idx, cursor,
                                                                  sorted_src, E);
    }
    {
        long long threads = (long long)N * 64;
        int block = 256;
        int grid = (int)((threads + block - 1) / block);
        gather_kernel<<<grid, block, 0, stream>>>((const float4*)q, (const float4*)k,
                                                  (const float4*)v, rowptr, sorted_src,
                                                  (float4*)d_out, N);
    }
}

// Round 5
// 166.016 us; speedup vs baseline: 8.5439x; 1.2437x over previous
//
#include <hip/hip_runtime.h>

// Sparse graph attention (CoreAttention), CSR-by-dst + packed-bf16 gather.
//   score[e,h] = exp(clip(dot(k[src],q[dst])/sqrt(D), -5, 5))
//   out[n,h,:] = sum_{e: dst==n} v[src]*score / (sum score + 1e-6)
// B=1, N=50000, H=8, D=16, E=800000.

#define HEADS 8
#define DIM 16

__device__ __forceinline__ unsigned f2bf(float f) {          // RNE f32->bf16 bits
    unsigned b = __float_as_uint(f);
    return (b + 0x7fffu + ((b >> 16) & 1u)) >> 16;
}
__device__ __forceinline__ float bflo(unsigned u) { return __uint_as_float(u << 16); }
__device__ __forceinline__ float bfhi(unsigned u) { return __uint_as_float(u & 0xffff0000u); }

// ---- Phase A: build CSR by destination ----

__global__ void hist_kernel(const int* __restrict__ dst_idx, int* __restrict__ counts, int E) {
    int i = blockIdx.x * blockDim.x + threadIdx.x;
    int base = i * 4;
    if (base + 3 < E) {
        int4 d = *(const int4*)(dst_idx + base);
        atomicAdd(&counts[d.x], 1);
        atomicAdd(&counts[d.y], 1);
        atomicAdd(&counts[d.z], 1);
        atomicAdd(&counts[d.w], 1);
    } else {
        for (int e = base; e < E; ++e) atomicAdd(&counts[dst_idx[e]], 1);
    }
}

__global__ void scan1_kernel(const int* __restrict__ counts, int* __restrict__ scanned,
                             int* __restrict__ blocksums, int n) {
    __shared__ int sh[256];
    int i = blockIdx.x * 256 + threadIdx.x;
    sh[threadIdx.x] = (i < n) ? counts[i] : 0;
    __syncthreads();
    for (int off = 1; off < 256; off <<= 1) {
        int t = (threadIdx.x >= off) ? sh[threadIdx.x - off] : 0;
        __syncthreads();
        sh[threadIdx.x] += t;
        __syncthreads();
    }
    if (i < n) scanned[i] = sh[threadIdx.x];            // inclusive
    if (threadIdx.x == 255) blocksums[blockIdx.x] = sh[255];
}

// rowptr + inline scan of blocksums (each block reduces its own prefix).
__global__ void rowptr_kernel(const int* __restrict__ counts, const int* __restrict__ scanned,
                              const int* __restrict__ blocksums,
                              int* __restrict__ rowptr, int* __restrict__ cursor,
                              int n, int nb, int E) {
    __shared__ int red[256];
    int b = blockIdx.x;
    int t = threadIdx.x;
    int val = 0;
    for (int t2 = t; t2 < b; t2 += 256) val += blocksums[t2];
    red[t] = val;
    __syncthreads();
    for (int off = 128; off > 0; off >>= 1) {
        if (t < off) red[t] += red[t + off];
        __syncthreads();
    }
    int base = red[0];
    int i = b * 256 + t;
    if (i < n) {
        int ex = scanned[i] - counts[i] + base;          // exclusive prefix
        rowptr[i] = ex;
        cursor[i] = ex;
    }
    if (i == n) rowptr[n] = E;
}

__global__ void scatter_kernel(const int* __restrict__ src_idx, const int* __restrict__ dst_idx,
                               int* __restrict__ cursor, int* __restrict__ sorted_src, int E) {
    int i = blockIdx.x * blockDim.x + threadIdx.x;
    int base = i * 4;
    if (base + 3 < E) {
        int4 s = *(const int4*)(src_idx + base);
        int4 d = *(const int4*)(dst_idx + base);
        sorted_src[atomicAdd(&cursor[d.x], 1)] = s.x;
        sorted_src[atomicAdd(&cursor[d.y], 1)] = s.y;
        sorted_src[atomicAdd(&cursor[d.z], 1)] = s.z;
        sorted_src[atomicAdd(&cursor[d.w], 1)] = s.w;
    } else {
        for (int e = base; e < E; ++e)
            sorted_src[atomicAdd(&cursor[dst_idx[e]], 1)] = src_idx[e];
    }
}

// ---- bf16 pack: kv[node] = 512 B row = [k: 128 bf16][v: 128 bf16] ----
// thread -> 8 floats -> one uint4 (8 bf16). total threads = N*32.
__global__ void convert_kernel(const float4* __restrict__ k4, const float4* __restrict__ v4,
                               uint4* __restrict__ kv, int total) {
    int t = blockIdx.x * blockDim.x + threadIdx.x;
    if (t >= total) return;
    int node = t >> 5;
    int seg  = t & 31;
    int isv  = seg >> 4;
    int s    = seg & 15;
    const float4* srcp = isv ? v4 : k4;
    float4 a = srcp[(size_t)node * 32 + s * 2];
    float4 b = srcp[(size_t)node * 32 + s * 2 + 1];
    uint4 o;
    o.x = f2bf(a.x) | (f2bf(a.y) << 16);
    o.y = f2bf(a.z) | (f2bf(a.w) << 16);
    o.z = f2bf(b.x) | (f2bf(b.y) << 16);
    o.w = f2bf(b.z) | (f2bf(b.w) << 16);
    kv[(size_t)node * 32 + isv * 16 + s] = o;
}

// ---- Phase B (bf16): 8 edges/wave-iter, 8 lanes/edge, lane = head ----
// Per edge only 512 B (8 cache lines) touched; 4 gather instrs/lane/edge.
__global__ void gather_bf16_kernel(const float4* __restrict__ q4,
                                   const uint4* __restrict__ kv,
                                   const int* __restrict__ rowptr,
                                   const int* __restrict__ sorted_src,
                                   float4* __restrict__ out4, int n) {
    int wave = (blockIdx.x * blockDim.x + threadIdx.x) >> 6;
    if (wave >= n) return;
    int lane = threadIdx.x & 63;
    int g  = lane >> 3;              // edge slot
    int l8 = lane & 7;               // head

    size_t qbase = (size_t)wave * 32 + l8 * 4;
    float4 q0 = q4[qbase + 0], q1 = q4[qbase + 1], q2 = q4[qbase + 2], q3 = q4[qbase + 3];
    q0.x *= 0.25f; q0.y *= 0.25f; q0.z *= 0.25f; q0.w *= 0.25f;
    q1.x *= 0.25f; q1.y *= 0.25f; q1.z *= 0.25f; q1.w *= 0.25f;
    q2.x *= 0.25f; q2.y *= 0.25f; q2.z *= 0.25f; q2.w *= 0.25f;
    q3.x *= 0.25f; q3.y *= 0.25f; q3.z *= 0.25f; q3.w *= 0.25f;

    float4 a0 = make_float4(0,0,0,0), a1 = a0, a2 = a0, a3 = a0;
    float zsum = 0.f;
    int beg = rowptr[wave], end = rowptr[wave + 1];

    if (beg < end) {
        int src_cur = sorted_src[min(beg + g, end - 1)];
        for (int j = beg; j < end; j += 8) {
            int my = j + g;
            int src = src_cur;
            src_cur = sorted_src[min(j + 8 + g, end - 1)];

            size_t base = (size_t)src * 32 + l8 * 2;
            uint4 ka = kv[base],      kb = kv[base + 1];
            uint4 va = kv[base + 16], vb = kv[base + 17];

            float p = q0.x*bflo(ka.x) + q0.y*bfhi(ka.x) + q0.z*bflo(ka.y) + q0.w*bfhi(ka.y)
                    + q1.x*bflo(ka.z) + q1.y*bfhi(ka.z) + q1.z*bflo(ka.w) + q1.w*bfhi(ka.w)
                    + q2.x*bflo(kb.x) + q2.y*bfhi(kb.x) + q2.z*bflo(kb.y) + q2.w*bfhi(kb.y)
                    + q3.x*bflo(kb.z) + q3.y*bfhi(kb.z) + q3.z*bflo(kb.w) + q3.w*bfhi(kb.w);
            p = fminf(fmaxf(p, -5.f), 5.f);
            float s = __expf(p);
            if (my >= end) s = 0.f;

            a0.x += bflo(va.x)*s; a0.y += bfhi(va.x)*s; a0.z += bflo(va.y)*s; a0.w += bfhi(va.y)*s;
            a1.x += bflo(va.z)*s; a1.y += bfhi(va.z)*s; a1.z += bflo(va.w)*s; a1.w += bfhi(va.w)*s;
            a2.x += bflo(vb.x)*s; a2.y += bfhi(vb.x)*s; a2.z += bflo(vb.y)*s; a2.w += bfhi(vb.y)*s;
            a3.x += bflo(vb.z)*s; a3.y += bfhi(vb.z)*s; a3.z += bflo(vb.w)*s; a3.w += bfhi(vb.w)*s;
            zsum += s;
        }
    }

    #pragma unroll
    for (int off = 8; off <= 32; off <<= 1) {
        a0.x += __shfl_xor(a0.x, off, 64); a0.y += __shfl_xor(a0.y, off, 64);
        a0.z += __shfl_xor(a0.z, off, 64); a0.w += __shfl_xor(a0.w, off, 64);
        a1.x += __shfl_xor(a1.x, off, 64); a1.y += __shfl_xor(a1.y, off, 64);
        a1.z += __shfl_xor(a1.z, off, 64); a1.w += __shfl_xor(a1.w, off, 64);
        a2.x += __shfl_xor(a2.x, off, 64); a2.y += __shfl_xor(a2.y, off, 64);
        a2.z += __shfl_xor(a2.z, off, 64); a2.w += __shfl_xor(a2.w, off, 64);
        a3.x += __shfl_xor(a3.x, off, 64); a3.y += __shfl_xor(a3.y, off, 64);
        a3.z += __shfl_xor(a3.z, off, 64); a3.w += __shfl_xor(a3.w, off, 64);
        zsum += __shfl_xor(zsum, off, 64);
    }

    float inv = 1.f / (zsum + 1e-6f);
    if (g == 0) {
        out4[qbase + 0] = make_float4(a0.x*inv, a0.y*inv, a0.z*inv, a0.w*inv);
        out4[qbase + 1] = make_float4(a1.x*inv, a1.y*inv, a1.z*inv, a1.w*inv);
        out4[qbase + 2] = make_float4(a2.x*inv, a2.y*inv, a2.z*inv, a2.w*inv);
        out4[qbase + 3] = make_float4(a3.x*inv, a3.y*inv, a3.z*inv, a3.w*inv);
    }
}

// ---- Phase B fallback (f32, R4 version) — used only if ws too small ----
__global__ void gather_f32_kernel(const float4* __restrict__ q4, const float4* __restrict__ k4,
                                  const float4* __restrict__ v4,
                                  const int* __restrict__ rowptr, const int* __restrict__ sorted_src,
                                  float4* __restrict__ out4, int n) {
    int wave = (blockIdx.x * blockDim.x + threadIdx.x) >> 6;
    if (wave >= n) return;
    int lane = threadIdx.x & 63;
    int g  = lane >> 3;
    int l8 = lane & 7;

    size_t qbase = (size_t)wave * 32 + l8 * 4;
    float4 q0 = q4[qbase + 0], q1 = q4[qbase + 1], q2 = q4[qbase + 2], q3 = q4[qbase + 3];
    q0.x *= 0.25f; q0.y *= 0.25f; q0.z *= 0.25f; q0.w *= 0.25f;
    q1.x *= 0.25f; q1.y *= 0.25f; q1.z *= 0.25f; q1.w *= 0.25f;
    q2.x *= 0.25f; q2.y *= 0.25f; q2.z *= 0.25f; q2.w *= 0.25f;
    q3.x *= 0.25f; q3.y *= 0.25f; q3.z *= 0.25f; q3.w *= 0.25f;

    float4 a0 = make_float4(0,0,0,0), a1 = a0, a2 = a0, a3 = a0;
    float zsum = 0.f;
    int beg = rowptr[wave], end = rowptr[wave + 1];

    if (beg < end) {
        int src_cur = sorted_src[min(beg + g, end - 1)];
        for (int j = beg; j < end; j += 8) {
            int my = j + g;
            int src = src_cur;
            src_cur = sorted_src[min(j + 8 + g, end - 1)];
            size_t base = (size_t)src * 32 + l8 * 4;
            float4 k0 = k4[base + 0], k1 = k4[base + 1], k2 = k4[base + 2], k3 = k4[base + 3];
            float p = q0.x*k0.x + q0.y*k0.y + q0.z*k0.z + q0.w*k0.w
                    + q1.x*k1.x + q1.y*k1.y + q1.z*k1.z + q1.w*k1.w
                    + q2.x*k2.x + q2.y*k2.y + q2.z*k2.z + q2.w*k2.w
                    + q3.x*k3.x + q3.y*k3.y + q3.z*k3.z + q3.w*k3.w;
            p = fminf(fmaxf(p, -5.f), 5.f);
            float score = __expf(p);
            if (my >= end) score = 0.f;
            float4 v0 = v4[base + 0], v1 = v4[base + 1], v2 = v4[base + 2], v3 = v4[base + 3];
            a0.x += v0.x*score; a0.y += v0.y*score; a0.z += v0.z*score; a0.w += v0.w*score;
            a1.x += v1.x*score; a1.y += v1.y*score; a1.z += v1.z*score; a1.w += v1.w*score;
            a2.x += v2.x*score; a2.y += v2.y*score; a2.z += v2.z*score; a2.w += v2.w*score;
            a3.x += v3.x*score; a3.y += v3.y*score; a3.z += v3.z*score; a3.w += v3.w*score;
            zsum += score;
        }
    }

    #pragma unroll
    for (int off = 8; off <= 32; off <<= 1) {
        a0.x += __shfl_xor(a0.x, off, 64); a0.y += __shfl_xor(a0.y, off, 64);
        a0.z += __shfl_xor(a0.z, off, 64); a0.w += __shfl_xor(a0.w, off, 64);
        a1.x += __shfl_xor(a1.x, off, 64); a1.y += __shfl_xor(a1.y, off, 64);
        a1.z += __shfl_xor(a1.z, off, 64); a1.w += __shfl_xor(a1.w, off, 64);
        a2.x += __shfl_xor(a2.x, off, 64); a2.y += __shfl_xor(a2.y, off, 64);
        a2.z += __shfl_xor(a2.z, off, 64); a2.w += __shfl_xor(a2.w, off, 64);
        a3.x += __shfl_xor(a3.x, off, 64); a3.y += __shfl_xor(a3.y, off, 64);
        a3.z += __shfl_xor(a3.w, off, 64); a3.w += __shfl_xor(a3.w, off, 64);
        zsum += __shfl_xor(zsum, off, 64);
    }

    float inv = 1.f / (zsum + 1e-6f);
    if (g == 0) {
        out4[qbase + 0] = make_float4(a0.x*inv, a0.y*inv, a0.z*inv, a0.w*inv);
        out4[qbase + 1] = make_float4(a1.x*inv, a1.y*inv, a1.z*inv, a1.w*inv);
        out4[qbase + 2] = make_float4(a2.x*inv, a2.y*inv, a2.z*inv, a2.w*inv);
        out4[qbase + 3] = make_float4(a3.x*inv, a3.y*inv, a3.z*inv, a3.w*inv);
    }
}

extern "C" void kernel_launch(void* const* d_in, const int* in_sizes, int n_in,
                              void* d_out, int out_size, void* d_ws, size_t ws_size,
                              hipStream_t stream) {
    const float* q = (const float*)d_in[0];
    const float* k = (const float*)d_in[1];
    const float* v = (const float*)d_in[2];
    const int* edge = (const int*)d_in[3];

    const int E = in_sizes[3] / 2;
    const int N = in_sizes[0] / (HEADS * DIM);
    const int nb = (N + 255) / 256;

    const int* src_idx = edge;
    const int* dst_idx = edge + E;

    // workspace layout: ints first, then 256B-aligned bf16 kv buffer
    int* counts     = (int*)d_ws;
    int* scanned    = counts + N;
    int* rowptr     = scanned + N;
    int* cursor     = rowptr + (N + 1);
    int* blocksums  = cursor + N;
    int* sorted_src = blocksums + 256;
    size_t int_count = (size_t)4 * N + 1 + 256 + (size_t)E;
    size_t kv_off = ((int_count * 4) + 255) & ~(size_t)255;
    uint4* kv = (uint4*)((char*)d_ws + kv_off);
    size_t needed = kv_off + (size_t)N * 512;
    bool use_bf16 = (ws_size >= needed);

    hipMemsetAsync(counts, 0, (size_t)N * sizeof(int), stream);

    if (use_bf16) {
        int total = N * 32;
        convert_kernel<<<(total + 255) / 256, 256, 0, stream>>>((const float4*)k,
                                                                (const float4*)v, kv, total);
    }
    {
        int threads = (E + 3) / 4;
        hist_kernel<<<(threads + 255) / 256, 256, 0, stream>>>(dst_idx, counts, E);
    }
    scan1_kernel<<<nb, 256, 0, stream>>>(counts, scanned, blocksums, N);
    {
        int blocks = (N + 256) / 256;
        rowptr_kernel<<<blocks, 256, 0, stream>>>(counts, scanned, blocksums,
                                                  rowptr, cursor, N, nb, E);
    }
    {
        int threads = (E + 3) / 4;
        scatter_kernel<<<(threads + 255) / 256, 256, 0, stream>>>(src_idx, dst_idx, cursor,
                                                                  sorted_src, E);
    }
    {
        long long threads = (long long)N * 64;
        int block = 256;
        int grid = (int)((threads + block - 1) / block);
        if (use_bf16) {
            gather_bf16_kernel<<<grid, block, 0, stream>>>((const float4*)q, kv,
                                                           rowptr, sorted_src,
                                                           (float4*)d_out, N);
        } else {
            gather_f32_kernel<<<grid, block, 0, stream>>>((const float4*)q, (const float4*)k,
                                                          (const float4*)v, rowptr, sorted_src,
                                                          (float4*)d_out, N);
        }
    }
}

// Round 6
// 161.139 us; speedup vs baseline: 8.8025x; 1.0303x over previous
//
#include <hip/hip_runtime.h>

// Sparse graph attention (CoreAttention), CSR-by-dst + packed-bf16 gather.
//   score[e,h] = exp(clip(dot(k[src],q[dst])/sqrt(D), -5, 5))
//   out[n,h,:] = sum_{e: dst==n} v[src]*score / (sum score + 1e-6)
// B=1, N=50000, H=8, D=16, E=800000.
// kv row layout (512 B): [k half0: heads 0-7][k half1: heads 0-7][v half0][v half1]
// (granule = 16 B = 8 bf16; transposed so each wave-instr reads contiguous 128 B/edge)

#define HEADS 8
#define DIM 16

__device__ __forceinline__ unsigned f2bf(float f) {          // RNE f32->bf16 bits
    unsigned b = __float_as_uint(f);
    return (b + 0x7fffu + ((b >> 16) & 1u)) >> 16;
}
__device__ __forceinline__ float bflo(unsigned u) { return __uint_as_float(u << 16); }
__device__ __forceinline__ float bfhi(unsigned u) { return __uint_as_float(u & 0xffff0000u); }

// ---- fused bf16-pack + dst histogram ----
// convert: thread t < total (= N*32) packs 8 floats -> uint4 (8 bf16), transposed granules.
// hist: thread t < (E+3)/4 also histograms 4 edges.
__global__ void convert_hist_kernel(const float4* __restrict__ k4, const float4* __restrict__ v4,
                                    uint4* __restrict__ kv,
                                    const int* __restrict__ dst_idx, int* __restrict__ counts,
                                    int total, int E) {
    int t = blockIdx.x * blockDim.x + threadIdx.x;
    if (t < total) {
        int node = t >> 5;
        int seg  = t & 31;
        int isv  = seg >> 4;
        int s    = seg & 15;              // source float4-pair index: head s>>1, half s&1
        const float4* srcp = isv ? v4 : k4;
        float4 a = srcp[(size_t)node * 32 + s * 2];
        float4 b = srcp[(size_t)node * 32 + s * 2 + 1];
        uint4 o;
        o.x = f2bf(a.x) | (f2bf(a.y) << 16);
        o.y = f2bf(a.z) | (f2bf(a.w) << 16);
        o.z = f2bf(b.x) | (f2bf(b.y) << 16);
        o.w = f2bf(b.z) | (f2bf(b.w) << 16);
        kv[(size_t)node * 32 + isv * 16 + (s & 1) * 8 + (s >> 1)] = o;
    }
    int base = t * 4;
    if (base + 3 < E) {
        int4 d = *(const int4*)(dst_idx + base);
        atomicAdd(&counts[d.x], 1);
        atomicAdd(&counts[d.y], 1);
        atomicAdd(&counts[d.z], 1);
        atomicAdd(&counts[d.w], 1);
    } else if (base < E) {
        for (int e = base; e < E; ++e) atomicAdd(&counts[dst_idx[e]], 1);
    }
}

__global__ void scan1_kernel(const int* __restrict__ counts, int* __restrict__ scanned,
                             int* __restrict__ blocksums, int n) {
    __shared__ int sh[256];
    int i = blockIdx.x * 256 + threadIdx.x;
    sh[threadIdx.x] = (i < n) ? counts[i] : 0;
    __syncthreads();
    for (int off = 1; off < 256; off <<= 1) {
        int t = (threadIdx.x >= off) ? sh[threadIdx.x - off] : 0;
        __syncthreads();
        sh[threadIdx.x] += t;
        __syncthreads();
    }
    if (i < n) scanned[i] = sh[threadIdx.x];            // inclusive
    if (threadIdx.x == 255) blocksums[blockIdx.x] = sh[255];
}

// rowptr + inline scan of blocksums (each block reduces its own prefix).
__global__ void rowptr_kernel(const int* __restrict__ counts, const int* __restrict__ scanned,
                              const int* __restrict__ blocksums,
                              int* __restrict__ rowptr, int* __restrict__ cursor,
                              int n, int nb, int E) {
    __shared__ int red[256];
    int b = blockIdx.x;
    int t = threadIdx.x;
    int val = 0;
    for (int t2 = t; t2 < b; t2 += 256) val += blocksums[t2];
    red[t] = val;
    __syncthreads();
    for (int off = 128; off > 0; off >>= 1) {
        if (t < off) red[t] += red[t + off];
        __syncthreads();
    }
    int base = red[0];
    int i = b * 256 + t;
    if (i < n) {
        int ex = scanned[i] - counts[i] + base;          // exclusive prefix
        rowptr[i] = ex;
        cursor[i] = ex;
    }
    if (i == n) rowptr[n] = E;
}

__global__ void scatter_kernel(const int* __restrict__ src_idx, const int* __restrict__ dst_idx,
                               int* __restrict__ cursor, int* __restrict__ sorted_src, int E) {
    int i = blockIdx.x * blockDim.x + threadIdx.x;
    int base = i * 4;
    if (base + 3 < E) {
        int4 s = *(const int4*)(src_idx + base);
        int4 d = *(const int4*)(dst_idx + base);
        sorted_src[atomicAdd(&cursor[d.x], 1)] = s.x;
        sorted_src[atomicAdd(&cursor[d.y], 1)] = s.y;
        sorted_src[atomicAdd(&cursor[d.z], 1)] = s.z;
        sorted_src[atomicAdd(&cursor[d.w], 1)] = s.w;
    } else {
        for (int e = base; e < E; ++e)
            sorted_src[atomicAdd(&cursor[dst_idx[e]], 1)] = src_idx[e];
    }
}

// ---- Phase B (bf16): 8 edges/wave-iter, 8 lanes/edge, lane = head ----
// Transposed granules: each load instr reads a contiguous 128 B block per edge
// (2 cache lines, vs 4 with the [head][half] layout) -> 8 line-requests/edge.
__global__ void gather_bf16_kernel(const float4* __restrict__ q4,
                                   const uint4* __restrict__ kv,
                                   const int* __restrict__ rowptr,
                                   const int* __restrict__ sorted_src,
                                   float4* __restrict__ out4, int n) {
    int wave = (blockIdx.x * blockDim.x + threadIdx.x) >> 6;
    if (wave >= n) return;
    int lane = threadIdx.x & 63;
    int g  = lane >> 3;              // edge slot
    int l8 = lane & 7;               // head

    size_t qbase = (size_t)wave * 32 + l8 * 4;
    float4 q0 = q4[qbase + 0], q1 = q4[qbase + 1], q2 = q4[qbase + 2], q3 = q4[qbase + 3];
    q0.x *= 0.25f; q0.y *= 0.25f; q0.z *= 0.25f; q0.w *= 0.25f;
    q1.x *= 0.25f; q1.y *= 0.25f; q1.z *= 0.25f; q1.w *= 0.25f;
    q2.x *= 0.25f; q2.y *= 0.25f; q2.z *= 0.25f; q2.w *= 0.25f;
    q3.x *= 0.25f; q3.y *= 0.25f; q3.z *= 0.25f; q3.w *= 0.25f;

    float4 a0 = make_float4(0,0,0,0), a1 = a0, a2 = a0, a3 = a0;
    float zsum = 0.f;
    int beg = rowptr[wave], end = rowptr[wave + 1];

    if (beg < end) {
        int src_cur = sorted_src[min(beg + g, end - 1)];
        for (int j = beg; j < end; j += 8) {
            int my = j + g;
            int src = src_cur;
            src_cur = sorted_src[min(j + 8 + g, end - 1)];

            size_t base = (size_t)src * 32;
            uint4 ka = kv[base + l8],      kb = kv[base + 8 + l8];
            uint4 va = kv[base + 16 + l8], vb = kv[base + 24 + l8];

            float p = q0.x*bflo(ka.x) + q0.y*bfhi(ka.x) + q0.z*bflo(ka.y) + q0.w*bfhi(ka.y)
                    + q1.x*bflo(ka.z) + q1.y*bfhi(ka.z) + q1.z*bflo(ka.w) + q1.w*bfhi(ka.w)
                    + q2.x*bflo(kb.x) + q2.y*bfhi(kb.x) + q2.z*bflo(kb.y) + q2.w*bfhi(kb.y)
                    + q3.x*bflo(kb.z) + q3.y*bfhi(kb.z) + q3.z*bflo(kb.w) + q3.w*bfhi(kb.w);
            p = fminf(fmaxf(p, -5.f), 5.f);
            float s = __expf(p);
            if (my >= end) s = 0.f;

            a0.x += bflo(va.x)*s; a0.y += bfhi(va.x)*s; a0.z += bflo(va.y)*s; a0.w += bfhi(va.y)*s;
            a1.x += bflo(va.z)*s; a1.y += bfhi(va.z)*s; a1.z += bflo(va.w)*s; a1.w += bfhi(va.w)*s;
            a2.x += bflo(vb.x)*s; a2.y += bfhi(vb.x)*s; a2.z += bflo(vb.y)*s; a2.w += bfhi(vb.y)*s;
            a3.x += bflo(vb.z)*s; a3.y += bfhi(vb.z)*s; a3.z += bflo(vb.w)*s; a3.w += bfhi(vb.w)*s;
            zsum += s;
        }
    }

    #pragma unroll
    for (int off = 8; off <= 32; off <<= 1) {
        a0.x += __shfl_xor(a0.x, off, 64); a0.y += __shfl_xor(a0.y, off, 64);
        a0.z += __shfl_xor(a0.z, off, 64); a0.w += __shfl_xor(a0.w, off, 64);
        a1.x += __shfl_xor(a1.x, off, 64); a1.y += __shfl_xor(a1.y, off, 64);
        a1.z += __shfl_xor(a1.z, off, 64); a1.w += __shfl_xor(a1.w, off, 64);
        a2.x += __shfl_xor(a2.x, off, 64); a2.y += __shfl_xor(a2.y, off, 64);
        a2.z += __shfl_xor(a2.z, off, 64); a2.w += __shfl_xor(a2.w, off, 64);
        a3.x += __shfl_xor(a3.x, off, 64); a3.y += __shfl_xor(a3.y, off, 64);
        a3.z += __shfl_xor(a3.z, off, 64); a3.w += __shfl_xor(a3.w, off, 64);
        zsum += __shfl_xor(zsum, off, 64);
    }

    float inv = 1.f / (zsum + 1e-6f);
    if (g == 0) {
        out4[qbase + 0] = make_float4(a0.x*inv, a0.y*inv, a0.z*inv, a0.w*inv);
        out4[qbase + 1] = make_float4(a1.x*inv, a1.y*inv, a1.z*inv, a1.w*inv);
        out4[qbase + 2] = make_float4(a2.x*inv, a2.y*inv, a2.z*inv, a2.w*inv);
        out4[qbase + 3] = make_float4(a3.x*inv, a3.y*inv, a3.z*inv, a3.w*inv);
    }
}

// ---- fallback path (f32 gather + standalone hist), used only if ws too small ----
__global__ void hist_kernel(const int* __restrict__ dst_idx, int* __restrict__ counts, int E) {
    int i = blockIdx.x * blockDim.x + threadIdx.x;
    int base = i * 4;
    if (base + 3 < E) {
        int4 d = *(const int4*)(dst_idx + base);
        atomicAdd(&counts[d.x], 1);
        atomicAdd(&counts[d.y], 1);
        atomicAdd(&counts[d.z], 1);
        atomicAdd(&counts[d.w], 1);
    } else {
        for (int e = base; e < E; ++e) atomicAdd(&counts[dst_idx[e]], 1);
    }
}

__global__ void gather_f32_kernel(const float4* __restrict__ q4, const float4* __restrict__ k4,
                                  const float4* __restrict__ v4,
                                  const int* __restrict__ rowptr, const int* __restrict__ sorted_src,
                                  float4* __restrict__ out4, int n) {
    int wave = (blockIdx.x * blockDim.x + threadIdx.x) >> 6;
    if (wave >= n) return;
    int lane = threadIdx.x & 63;
    int g  = lane >> 3;
    int l8 = lane & 7;

    size_t qbase = (size_t)wave * 32 + l8 * 4;
    float4 q0 = q4[qbase + 0], q1 = q4[qbase + 1], q2 = q4[qbase + 2], q3 = q4[qbase + 3];
    q0.x *= 0.25f; q0.y *= 0.25f; q0.z *= 0.25f; q0.w *= 0.25f;
    q1.x *= 0.25f; q1.y *= 0.25f; q1.z *= 0.25f; q1.w *= 0.25f;
    q2.x *= 0.25f; q2.y *= 0.25f; q2.z *= 0.25f; q2.w *= 0.25f;
    q3.x *= 0.25f; q3.y *= 0.25f; q3.z *= 0.25f; q3.w *= 0.25f;

    float4 a0 = make_float4(0,0,0,0), a1 = a0, a2 = a0, a3 = a0;
    float zsum = 0.f;
    int beg = rowptr[wave], end = rowptr[wave + 1];

    if (beg < end) {
        int src_cur = sorted_src[min(beg + g, end - 1)];
        for (int j = beg; j < end; j += 8) {
            int my = j + g;
            int src = src_cur;
            src_cur = sorted_src[min(j + 8 + g, end - 1)];
            size_t base = (size_t)src * 32 + l8 * 4;
            float4 k0 = k4[base + 0], k1 = k4[base + 1], k2 = k4[base + 2], k3 = k4[base + 3];
            float p = q0.x*k0.x + q0.y*k0.y + q0.z*k0.z + q0.w*k0.w
                    + q1.x*k1.x + q1.y*k1.y + q1.z*k1.z + q1.w*k1.w
                    + q2.x*k2.x + q2.y*k2.y + q2.z*k2.z + q2.w*k2.w
                    + q3.x*k3.x + q3.y*k3.y + q3.z*k3.z + q3.w*k3.w;
            p = fminf(fmaxf(p, -5.f), 5.f);
            float score = __expf(p);
            if (my >= end) score = 0.f;
            float4 v0 = v4[base + 0], v1 = v4[base + 1], v2 = v4[base + 2], v3 = v4[base + 3];
            a0.x += v0.x*score; a0.y += v0.y*score; a0.z += v0.z*score; a0.w += v0.w*score;
            a1.x += v1.x*score; a1.y += v1.y*score; a1.z += v1.z*score; a1.w += v1.w*score;
            a2.x += v2.x*score; a2.y += v2.y*score; a2.z += v2.z*score; a2.w += v2.w*score;
            a3.x += v3.x*score; a3.y += v3.y*score; a3.z += v3.z*score; a3.w += v3.w*score;
            zsum += score;
        }
    }

    #pragma unroll
    for (int off = 8; off <= 32; off <<= 1) {
        a0.x += __shfl_xor(a0.x, off, 64); a0.y += __shfl_xor(a0.y, off, 64);
        a0.z += __shfl_xor(a0.z, off, 64); a0.w += __shfl_xor(a0.w, off, 64);
        a1.x += __shfl_xor(a1.x, off, 64); a1.y += __shfl_xor(a1.y, off, 64);
        a1.z += __shfl_xor(a1.z, off, 64); a1.w += __shfl_xor(a1.w, off, 64);
        a2.x += __shfl_xor(a2.x, off, 64); a2.y += __shfl_xor(a2.y, off, 64);
        a2.z += __shfl_xor(a2.z, off, 64); a2.w += __shfl_xor(a2.w, off, 64);
        a3.x += __shfl_xor(a3.x, off, 64); a3.y += __shfl_xor(a3.y, off, 64);
        a3.z += __shfl_xor(a3.z, off, 64); a3.w += __shfl_xor(a3.w, off, 64);
        zsum += __shfl_xor(zsum, off, 64);
    }

    float inv = 1.f / (zsum + 1e-6f);
    if (g == 0) {
        out4[qbase + 0] = make_float4(a0.x*inv, a0.y*inv, a0.z*inv, a0.w*inv);
        out4[qbase + 1] = make_float4(a1.x*inv, a1.y*inv, a1.z*inv, a1.w*inv);
        out4[qbase + 2] = make_float4(a2.x*inv, a2.y*inv, a2.z*inv, a2.w*inv);
        out4[qbase + 3] = make_float4(a3.x*inv, a3.y*inv, a3.z*inv, a3.w*inv);
    }
}

extern "C" void kernel_launch(void* const* d_in, const int* in_sizes, int n_in,
                              void* d_out, int out_size, void* d_ws, size_t ws_size,
                              hipStream_t stream) {
    const float* q = (const float*)d_in[0];
    const float* k = (const float*)d_in[1];
    const float* v = (const float*)d_in[2];
    const int* edge = (const int*)d_in[3];

    const int E = in_sizes[3] / 2;
    const int N = in_sizes[0] / (HEADS * DIM);
    const int nb = (N + 255) / 256;

    const int* src_idx = edge;
    const int* dst_idx = edge + E;

    // workspace layout: ints first, then 256B-aligned bf16 kv buffer
    int* counts     = (int*)d_ws;
    int* scanned    = counts + N;
    int* rowptr     = scanned + N;
    int* cursor     = rowptr + (N + 1);
    int* blocksums  = cursor + N;
    int* sorted_src = blocksums + 256;
    size_t int_count = (size_t)4 * N + 1 + 256 + (size_t)E;
    size_t kv_off = ((int_count * 4) + 255) & ~(size_t)255;
    uint4* kv = (uint4*)((char*)d_ws + kv_off);
    size_t needed = kv_off + (size_t)N * 512;
    bool use_bf16 = (ws_size >= needed);

    hipMemsetAsync(counts, 0, (size_t)N * sizeof(int), stream);

    if (use_bf16) {
        int total = N * 32;                       // convert work >= hist work
        convert_hist_kernel<<<(total + 255) / 256, 256, 0, stream>>>(
            (const float4*)k, (const float4*)v, kv, dst_idx, counts, total, E);
    } else {
        int threads = (E + 3) / 4;
        hist_kernel<<<(threads + 255) / 256, 256, 0, stream>>>(dst_idx, counts, E);
    }
    scan1_kernel<<<nb, 256, 0, stream>>>(counts, scanned, blocksums, N);
    {
        int blocks = (N + 256) / 256;
        rowptr_kernel<<<blocks, 256, 0, stream>>>(counts, scanned, blocksums,
                                                  rowptr, cursor, N, nb, E);
    }
    {
        int threads = (E + 3) / 4;
        scatter_kernel<<<(threads + 255) / 256, 256, 0, stream>>>(src_idx, dst_idx, cursor,
                                                                  sorted_src, E);
    }
    {
        long long threads = (long long)N * 64;
        int block = 256;
        int grid = (int)((threads + block - 1) / block);
        if (use_bf16) {
            gather_bf16_kernel<<<grid, block, 0, stream>>>((const float4*)q, kv,
                                                           rowptr, sorted_src,
                                                           (float4*)d_out, N);
        } else {
            gather_f32_kernel<<<grid, block, 0, stream>>>((const float4*)q, (const float4*)k,
                                                          (const float4*)v, rowptr, sorted_src,
                                                          (float4*)d_out, N);
        }
    }
}